// Round 14
// baseline (366.876 us; speedup 1.0000x reference)
//
#include <hip/hip_runtime.h>
#include <hip/hip_bf16.h>

#define Ndim 4096
#define Edim 8192
#define Fdim 256
#define Bdim 16
#define NT (Edim / 64)     // 128 K-tiles of BK=64

typedef __attribute__((ext_vector_type(8))) short bf16x8;
typedef __attribute__((ext_vector_type(16))) float f32x16;

__device__ __forceinline__ unsigned short f2bf(float f) {
  unsigned int u = __float_as_uint(f);
  u += 0x7fffu + ((u >> 16) & 1u);   // round-to-nearest-even
  return (unsigned short)(u >> 16);
}

__device__ __forceinline__ void gload_lds16(const void* g, void* l) {
  __builtin_amdgcn_global_load_lds(
      (const __attribute__((address_space(1))) unsigned int*)g,
      (__attribute__((address_space(3))) unsigned int*)l, 16, 0, 0);
}

// stage one packed 16KB half (1024 slots): 512 threads x 2 x 16B, linear both sides
__device__ __forceinline__ void stage_half(const char* g, char* d) {
  gload_lds16(g, d);
  gload_lds16(g + 8192, d + 8192);
}

#define FENCE() asm volatile("" ::: "memory")

// ---------------- pass 1a: A'[(mt*128+kt)*2+h][c][r] = bf16(w*inci+b) ----------------
// slot = region*1024 + c*128 + r ; 16B per slot (8 bf16 of consecutive e)
__global__ void convert_m_p(const float* __restrict__ w, const float* __restrict__ inc,
                            const float* __restrict__ bb, unsigned short* __restrict__ Ap) {
  const int nt = blockIdx.x;       // 128 tiles of 32 n-rows
  const int kt = blockIdx.y;       // 128 K-tiles
  const int tid = threadIdx.x;
  const int nn = tid >> 3, c = tid & 7;
  const int n = nt * 32 + nn;
  const int mt = n >> 8, h = (n >> 7) & 1, r = n & 127;
  const size_t ein = (size_t)n * Edim + kt * 64 + c * 8;
  float4 w0 = *(const float4*)(w + ein),  w1 = *(const float4*)(w + ein + 4);
  float4 i0 = *(const float4*)(inc + ein), i1 = *(const float4*)(inc + ein + 4);
  float4 b0 = *(const float4*)(bb + ein),  b1 = *(const float4*)(bb + ein + 4);
  bf16x8 o;
  o[0] = (short)f2bf(fmaf(w0.x, i0.x, b0.x));
  o[1] = (short)f2bf(fmaf(w0.y, i0.y, b0.y));
  o[2] = (short)f2bf(fmaf(w0.z, i0.z, b0.z));
  o[3] = (short)f2bf(fmaf(w0.w, i0.w, b0.w));
  o[4] = (short)f2bf(fmaf(w1.x, i1.x, b1.x));
  o[5] = (short)f2bf(fmaf(w1.y, i1.y, b1.y));
  o[6] = (short)f2bf(fmaf(w1.z, i1.z, b1.z));
  o[7] = (short)f2bf(fmaf(w1.w, i1.w, b1.w));
  const size_t slot = ((size_t)(mt * 128 + kt) * 2 + h) * 1024 + c * 128 + r;
  *(bf16x8*)(Ap + slot * 8) = o;
}

// ---------------- pass 1b: B'[(bb*128+kt)*2+h][c][r] = bf16(x transposed) ----------------
// thread owns 16 consecutive e for one f -> two 16B output slots; no LDS needed
__global__ void transpose_x_p(const float* __restrict__ x, unsigned short* __restrict__ Bp) {
  const int kt = blockIdx.x, f0 = blockIdx.y * 64, b = blockIdx.z;
  const int tid = threadIdx.x;
  const int fl = tid & 63, rq = tid >> 6;
  const float* xb = x + (size_t)b * Edim * Fdim;
  const int e0 = kt * 64 + rq * 16;
  const int f = f0 + fl;
  unsigned short v[16];
#pragma unroll
  for (int i = 0; i < 16; ++i)
    v[i] = f2bf(xb[(size_t)(e0 + i) * Fdim + f]);
  const int h = f0 >> 7;
  const int r = (f0 & 127) + fl;
  const size_t base = ((size_t)(b * 128 + kt) * 2 + h) * 1024;
#pragma unroll
  for (int j = 0; j < 2; ++j) {
    bf16x8 o;
#pragma unroll
    for (int k = 0; k < 8; ++k) o[k] = (short)v[j * 8 + k];
    const int c = rq * 2 + j;
    *(bf16x8*)(Bp + (base + c * 128 + r) * 8) = o;
  }
}

// ---- GEMM: 256x256 tile, 8 waves, 32x32x16 MFMA, packed chunk-major LDS ----
// LDS buffer u @ u*65536: A [h][c][r] 2*8*128*16B = 32768 ; B same @ +32768.
// Frag reads are LINEAR (consecutive lanes -> consecutive rows) = conflict-free.
// Phases (4 barriers/tile), k-step p per phase:
//  P1: stage A(t+1)h0->other; BAR; MFMA k0; read k1(cur)
//  P2: stage A(t+1)h1->other; BAR; MFMA k1; read k2
//  P3:                        BAR; MFMA k2; read k3
//  P4: BAR; stage B(t+2)->cur (after BAR => provably WAR-safe vs P3-tail reads);
//      MFMA k3; vmcnt(4) [drains (t+1).A+B exactly]; read k0-next (other)
template <int MODE>
__device__ __forceinline__ void ktile(
    const char* cb, const char* ob,
    char* dOther, const char* gA1,   // A(t+1) stage dst/src (h0; h1 at +16384)
    char* dCur, const char* gB2,     // B(t+2) stage dst/src
    const int (&aB)[4], const int (&bB)[2], const int (&cO)[4],
    bf16x8 (&aC)[4], bf16x8 (&bC)[2], f32x16 acc[4][2]) {
  // ---- P1 ----
  if constexpr (MODE >= 1) stage_half(gA1, dOther);
  __builtin_amdgcn_s_barrier(); FENCE();
  __builtin_amdgcn_s_setprio(1);
#pragma unroll
  for (int m = 0; m < 4; ++m)
#pragma unroll
    for (int n = 0; n < 2; ++n)
      acc[m][n] = __builtin_amdgcn_mfma_f32_32x32x16_bf16(aC[m], bC[n], acc[m][n], 0, 0, 0);
  __builtin_amdgcn_s_setprio(0);
#pragma unroll
  for (int m = 0; m < 4; ++m) aC[m] = *(const bf16x8*)(cb + aB[m] + cO[1]);
#pragma unroll
  for (int n = 0; n < 2; ++n) bC[n] = *(const bf16x8*)(cb + bB[n] + cO[1]);

  // ---- P2 ----
  if constexpr (MODE >= 1) stage_half(gA1 + 16384, dOther + 16384);
  __builtin_amdgcn_s_barrier(); FENCE();
  __builtin_amdgcn_s_setprio(1);
#pragma unroll
  for (int m = 0; m < 4; ++m)
#pragma unroll
    for (int n = 0; n < 2; ++n)
      acc[m][n] = __builtin_amdgcn_mfma_f32_32x32x16_bf16(aC[m], bC[n], acc[m][n], 0, 0, 0);
  __builtin_amdgcn_s_setprio(0);
#pragma unroll
  for (int m = 0; m < 4; ++m) aC[m] = *(const bf16x8*)(cb + aB[m] + cO[2]);
#pragma unroll
  for (int n = 0; n < 2; ++n) bC[n] = *(const bf16x8*)(cb + bB[n] + cO[2]);

  // ---- P3 ----
  __builtin_amdgcn_s_barrier(); FENCE();
  __builtin_amdgcn_s_setprio(1);
#pragma unroll
  for (int m = 0; m < 4; ++m)
#pragma unroll
    for (int n = 0; n < 2; ++n)
      acc[m][n] = __builtin_amdgcn_mfma_f32_32x32x16_bf16(aC[m], bC[n], acc[m][n], 0, 0, 0);
  __builtin_amdgcn_s_setprio(0);
#pragma unroll
  for (int m = 0; m < 4; ++m) aC[m] = *(const bf16x8*)(cb + aB[m] + cO[3]);
#pragma unroll
  for (int n = 0; n < 2; ++n) bC[n] = *(const bf16x8*)(cb + bB[n] + cO[3]);

  // ---- P4 ----
  __builtin_amdgcn_s_barrier(); FENCE();
  if constexpr (MODE == 2) {
    stage_half(gB2, dCur + 32768);
    stage_half(gB2 + 16384, dCur + 49152);
  }
  __builtin_amdgcn_s_setprio(1);
#pragma unroll
  for (int m = 0; m < 4; ++m)
#pragma unroll
    for (int n = 0; n < 2; ++n)
      acc[m][n] = __builtin_amdgcn_mfma_f32_32x32x16_bf16(aC[m], bC[n], acc[m][n], 0, 0, 0);
  __builtin_amdgcn_s_setprio(0);
  if constexpr (MODE == 2) asm volatile("s_waitcnt vmcnt(4)" ::: "memory");
  if constexpr (MODE == 1) asm volatile("s_waitcnt vmcnt(0)" ::: "memory");
  if constexpr (MODE >= 1) {
#pragma unroll
    for (int m = 0; m < 4; ++m) aC[m] = *(const bf16x8*)(ob + aB[m] + cO[0]);
#pragma unroll
    for (int n = 0; n < 2; ++n) bC[n] = *(const bf16x8*)(ob + bB[n] + cO[0]);
  }
}

__global__ __launch_bounds__(512, 2) void gemm32p(
    const unsigned short* __restrict__ Ap,   // packed A'
    const unsigned short* __restrict__ Bp,   // packed B'
    float* __restrict__ C) {                 // [Bdim][Ndim][Fdim] f32
  __shared__ __align__(16) char smem[131072];

  const int bid = blockIdx.x;
  const int lid = ((bid & 7) << 5) | (bid >> 3);  // XCD-contiguous (256 % 8 == 0)
  const int mt = lid >> 4;   // node tile 0..15
  const int bb = lid & 15;   // batch

  const int tid = threadIdx.x;
  const int lane = tid & 63;
  const int w = tid >> 6;
  const int wr = w >> 2;     // 0..1 (M: 2 x 128)
  const int wc = w & 3;      // 0..3 (N: 4 x 64)
  const int l31 = lane & 31;
  const int lh = lane >> 5;

  // frag read offsets (linear packed layout)
  int aB[4], bB[2], cO[4];
#pragma unroll
  for (int m = 0; m < 4; ++m) aB[m] = wr * 16384 + (m * 32 + l31) * 16;
#pragma unroll
  for (int n = 0; n < 2; ++n) {
    int rB = wc * 64 + n * 32 + l31;
    bB[n] = 32768 + (rB >> 7) * 16384 + (rB & 127) * 16;
  }
#pragma unroll
  for (int ks = 0; ks < 4; ++ks) cO[ks] = (ks * 2 + lh) * 2048;

  const char* AgT = (const char*)Ap + (size_t)mt * 128 * 32768 + tid * 16;
  const char* BgT = (const char*)Bp + (size_t)bb * 128 * 32768 + tid * 16;
  char* dstT = smem + tid * 16;

  f32x16 acc[4][2];
#pragma unroll
  for (int m = 0; m < 4; ++m)
#pragma unroll
    for (int n = 0; n < 2; ++n)
#pragma unroll
      for (int r = 0; r < 16; ++r) acc[m][n][r] = 0.f;

  // prologue: t0.A, t0.B -> buf0 ; t1.B -> buf1 (12 loads); vmcnt(4) leaves t1.B
  stage_half(AgT, dstT);
  stage_half(AgT + 16384, dstT + 16384);
  stage_half(BgT, dstT + 32768);
  stage_half(BgT + 16384, dstT + 49152);
  stage_half(BgT + 32768, dstT + 65536 + 32768);
  stage_half(BgT + 32768 + 16384, dstT + 65536 + 49152);
  asm volatile("s_waitcnt vmcnt(4)" ::: "memory");
  __builtin_amdgcn_s_barrier(); FENCE();

  bf16x8 aC[4], bC[2];
#pragma unroll
  for (int m = 0; m < 4; ++m) aC[m] = *(const bf16x8*)(smem + aB[m] + cO[0]);
#pragma unroll
  for (int n = 0; n < 2; ++n) bC[n] = *(const bf16x8*)(smem + bB[n] + cO[0]);

  for (int t = 0; t < NT - 2; ++t) {
    const int u = t & 1;
    const char* cb = smem + u * 65536;
    const char* ob = smem + (u ^ 1) * 65536;
    ktile<2>(cb, ob,
             dstT + (u ^ 1) * 65536, AgT + (size_t)(t + 1) * 32768,
             dstT + u * 65536, BgT + (size_t)(t + 2) * 32768,
             aB, bB, cO, aC, bC, acc);
  }
  // t = NT-2 (buf0): stage A(NT-1) only; vmcnt(0); tail k0 of NT-1
  ktile<1>(smem, smem + 65536,
           dstT + 65536, AgT + (size_t)(NT - 1) * 32768,
           dstT, nullptr,
           aB, bB, cO, aC, bC, acc);
  // t = NT-1 (buf1): compute only
  ktile<0>(smem + 65536, smem,
           nullptr, nullptr, nullptr, nullptr,
           aB, bB, cO, aC, bC, acc);

  // C/D layout (32x32, verified R8/m74/m101): col = lane&31,
  // row = (reg&3) + 8*(reg>>2) + 4*(lane>>5)
  float* Cb = C + (size_t)bb * (Ndim * Fdim) + (size_t)(mt * 256) * Fdim;
#pragma unroll
  for (int m = 0; m < 4; ++m)
#pragma unroll
    for (int n = 0; n < 2; ++n) {
      int col = wc * 64 + n * 32 + l31;
#pragma unroll
      for (int r = 0; r < 16; ++r) {
        int row = wr * 128 + m * 32 + (r & 3) + ((r >> 2) << 3) + (lh << 2);
        Cb[(size_t)row * Fdim + col] = acc[m][n][r];
      }
    }
}

// ---------------- fallback (ws too small): slow but correct fp32 ----------------
__global__ void naive_kernel(const float* __restrict__ x, const float* __restrict__ inci,
                             const float* __restrict__ w, const float* __restrict__ b,
                             float* __restrict__ out) {
  int n = blockIdx.x & (Ndim - 1);
  int bb = blockIdx.x >> 12;
  int f = threadIdx.x;
  const float* xb = x + (size_t)bb * Edim * Fdim;
  const size_t nE = (size_t)n * Edim;
  float acc = 0.f;
  for (int e = 0; e < Edim; e++) {
    float m = fmaf(w[nE + e], inci[nE + e], b[nE + e]);
    acc = fmaf(m, xb[(size_t)e * Fdim + f], acc);
  }
  out[(size_t)bb * Ndim * Fdim + (size_t)n * Fdim + f] = acc;
}

extern "C" void kernel_launch(void* const* d_in, const int* in_sizes, int n_in,
                              void* d_out, int out_size, void* d_ws, size_t ws_size,
                              hipStream_t stream) {
  const float* x = (const float*)d_in[0];
  const float* inci = (const float*)d_in[1];
  const float* w = (const float*)d_in[2];
  const float* b = (const float*)d_in[3];
  float* out = (float*)d_out;

  size_t aBytes = (size_t)Ndim * Edim * 2;
  size_t bBytes = (size_t)Bdim * Fdim * Edim * 2;
  if (ws_size >= aBytes + bBytes) {
    unsigned short* Ap = (unsigned short*)d_ws;
    unsigned short* Bp = Ap + (size_t)Ndim * Edim;
    convert_m_p<<<dim3(Ndim / 32, Edim / 64), 256, 0, stream>>>(w, inci, b, Ap);
    transpose_x_p<<<dim3(Edim / 64, Fdim / 64, Bdim), 256, 0, stream>>>(x, Bp);
    gemm32p<<<256, 512, 0, stream>>>(Ap, Bp, out);
  } else {
    naive_kernel<<<Bdim * Ndim, 256, 0, stream>>>(x, inci, w, b, out);
  }
}

// Round 15
// 333.255 us; speedup vs baseline: 1.1009x; 1.1009x over previous
//
#include <hip/hip_runtime.h>
#include <hip/hip_bf16.h>

#define Ndim 4096
#define Edim 8192
#define Fdim 256
#define Bdim 16
#define EB (Edim * 2)      // bf16 row bytes = 16384
#define NT (Edim / 64)     // 128 K-tiles of BK=64

typedef __attribute__((ext_vector_type(8))) short bf16x8;
typedef __attribute__((ext_vector_type(4))) float f32x4;

__device__ __forceinline__ unsigned short f2bf(float f) {
  unsigned int u = __float_as_uint(f);
  u += 0x7fffu + ((u >> 16) & 1u);   // round-to-nearest-even
  return (unsigned short)(u >> 16);
}

__device__ __forceinline__ void gload_lds16(const void* g, void* l) {
  __builtin_amdgcn_global_load_lds(
      (const __attribute__((address_space(1))) unsigned int*)g,
      (__attribute__((address_space(3))) unsigned int*)l, 16, 0, 0);
}

// stage one 128x64 half-matrix: 512 threads x 2 loads x 16B
__device__ __forceinline__ void stage_half(const char* g, char* d) {
  gload_lds16(g, d);
  gload_lds16(g + (size_t)64 * EB, d + 8192);
}

// swizzled LDS fragment read: logical (row r, 16B col block kk*64+khi)
#define RD(base, r, kk) \
  (*(const bf16x8*)((base) + (r) * 128 + ((((kk) * 64) + khi) ^ (((r) & 7) << 4))))

// ---------------- pass 1a: m_bf16 = bf16(w*inci + b) ----------------
__global__ void convert_m(const float* __restrict__ w, const float* __restrict__ inc,
                          const float* __restrict__ bb, unsigned short* __restrict__ m) {
  size_t i = ((size_t)blockIdx.x * 256 + threadIdx.x) * 4;
  float4 wv = *(const float4*)(w + i);
  float4 iv = *(const float4*)(inc + i);
  float4 bv = *(const float4*)(bb + i);
  ushort4 o;
  o.x = f2bf(fmaf(wv.x, iv.x, bv.x));
  o.y = f2bf(fmaf(wv.y, iv.y, bv.y));
  o.z = f2bf(fmaf(wv.z, iv.z, bv.z));
  o.w = f2bf(fmaf(wv.w, iv.w, bv.w));
  *(ushort4*)(m + i) = o;
}

// ---------------- pass 1b: xT[b][f][e] = bf16(x[b][e][f]) ----------------
__global__ void transpose_x(const float* __restrict__ x, unsigned short* __restrict__ xT) {
  __shared__ unsigned short tile[64][66];
  int e0 = blockIdx.x * 64, f0 = blockIdx.y * 64, b = blockIdx.z;
  const float* xb = x + (size_t)b * Edim * Fdim;
  unsigned short* xTb = xT + (size_t)b * Fdim * Edim;
  int t = threadIdx.x;
  int fl = t & 63, rq = t >> 6;
#pragma unroll
  for (int i = 0; i < 16; i++) {
    int el = rq * 16 + i;
    float v = xb[(size_t)(e0 + el) * Fdim + f0 + fl];
    tile[el][fl] = f2bf(v);
  }
  __syncthreads();
  int ep = (t & 31) * 2;
  int fr0 = t >> 5;
#pragma unroll
  for (int j = 0; j < 8; j++) {
    int fr = fr0 + j * 8;
    unsigned int pk = (unsigned int)tile[ep][fr] | ((unsigned int)tile[ep + 1][fr] << 16);
    *(unsigned int*)&xTb[(size_t)(f0 + fr) * Edim + e0 + ep] = pk;
  }
}

// -------- one K-tile = 4 phases; reads at prior-phase TAILS; tails 4/8/4/8 --
// P1: stage1; bar; MFMA Q00(aCur,bLoC)         tail: read bHi(4);      bar
// P2: stage2; bar; MFMA Q01(aCur,bHi)          tail: read aHi(8);      bar
// P3: stage3; bar; MFMA Q10(aHi,bLoC); vmcnt(2); tail: read next bLo(4); bar
// P4: stage4; bar; MFMA Q11(aHi,bHi)           tail: read next aLo(8); bar
// No manual lgkmcnt(0): frag loads are plain loads, compiler emits counted
// per-use lgkmcnt (finer than a full drain). vmcnt(2)@t.P3 drains t-1.S4 and
// t.S1/S2 -> tile t+1's A and B proven landed before the P3/P4 cross-buffer
// tail reads. WAR: each phase's reads complete before that wave's consuming
// MFMA (compiler wait) which precedes the phase's closing barrier; stages
// targeting a region are issued only after a barrier that post-dates all
// waves' reads of it (same map as R7, verified).
// MODE: 2 steady; 1 tile NT-2 (S1,S2 only, vmcnt(0)); 0 last (no stage/tail).
template <int MODE>
__device__ __forceinline__ void ktile(
    const char* lA, const char* lB, const char* lAn, const char* lBn,
    char* d1, const char* g1, char* d2, const char* g2,
    char* d3, const char* g3, char* d4, const char* g4,
    int lane, int wr, int wc,
    bf16x8 (&aCur)[8], bf16x8 (&bLoC)[4], f32x4 acc[8][4]) {
  const int l15 = lane & 15;
  const int khi = (lane >> 4) << 4;
  bf16x8 bHi[4], aHi[8];

  // ---- P1 ----
  if constexpr (MODE >= 1) stage_half(g1, d1);
  __builtin_amdgcn_s_barrier();
  __builtin_amdgcn_s_setprio(1);
#pragma unroll
  for (int m = 0; m < 4; ++m)
#pragma unroll
    for (int n = 0; n < 2; ++n)
#pragma unroll
      for (int kk = 0; kk < 2; ++kk)
        acc[m][n] = __builtin_amdgcn_mfma_f32_16x16x32_bf16(aCur[m * 2 + kk], bLoC[n * 2 + kk],
                                                            acc[m][n], 0, 0, 0);
  __builtin_amdgcn_s_setprio(0);
#pragma unroll
  for (int n = 0; n < 2; ++n)
#pragma unroll
    for (int kk = 0; kk < 2; ++kk)
      bHi[n * 2 + kk] = RD(lB, wc * 64 + (n + 2) * 16 + l15, kk);
  __builtin_amdgcn_s_barrier();

  // ---- P2 ----
  if constexpr (MODE >= 1) stage_half(g2, d2);
  __builtin_amdgcn_s_barrier();
  __builtin_amdgcn_s_setprio(1);
#pragma unroll
  for (int m = 0; m < 4; ++m)
#pragma unroll
    for (int n = 0; n < 2; ++n)
#pragma unroll
      for (int kk = 0; kk < 2; ++kk)
        acc[m][n + 2] = __builtin_amdgcn_mfma_f32_16x16x32_bf16(aCur[m * 2 + kk], bHi[n * 2 + kk],
                                                                acc[m][n + 2], 0, 0, 0);
  __builtin_amdgcn_s_setprio(0);
#pragma unroll
  for (int m = 0; m < 4; ++m)
#pragma unroll
    for (int kk = 0; kk < 2; ++kk)
      aHi[m * 2 + kk] = RD(lA, wr * 128 + 64 + m * 16 + l15, kk);
  __builtin_amdgcn_s_barrier();

  // ---- P3 ----
  if constexpr (MODE == 2) stage_half(g3, d3);
  __builtin_amdgcn_s_barrier();
  __builtin_amdgcn_s_setprio(1);
#pragma unroll
  for (int m = 0; m < 4; ++m)
#pragma unroll
    for (int n = 0; n < 2; ++n)
#pragma unroll
      for (int kk = 0; kk < 2; ++kk)
        acc[m + 4][n] = __builtin_amdgcn_mfma_f32_16x16x32_bf16(aHi[m * 2 + kk], bLoC[n * 2 + kk],
                                                                acc[m + 4][n], 0, 0, 0);
  __builtin_amdgcn_s_setprio(0);
  if constexpr (MODE == 2) asm volatile("s_waitcnt vmcnt(2)" ::: "memory");
  if constexpr (MODE == 1) asm volatile("s_waitcnt vmcnt(0)" ::: "memory");
  if constexpr (MODE >= 1) {
#pragma unroll
    for (int n = 0; n < 2; ++n)
#pragma unroll
      for (int kk = 0; kk < 2; ++kk)
        bLoC[n * 2 + kk] = RD(lBn, wc * 64 + n * 16 + l15, kk);
  }
  __builtin_amdgcn_s_barrier();

  // ---- P4 ----
  if constexpr (MODE == 2) stage_half(g4, d4);
  __builtin_amdgcn_s_barrier();
  __builtin_amdgcn_s_setprio(1);
#pragma unroll
  for (int m = 0; m < 4; ++m)
#pragma unroll
    for (int n = 0; n < 2; ++n)
#pragma unroll
      for (int kk = 0; kk < 2; ++kk)
        acc[m + 4][n + 2] = __builtin_amdgcn_mfma_f32_16x16x32_bf16(aHi[m * 2 + kk], bHi[n * 2 + kk],
                                                                    acc[m + 4][n + 2], 0, 0, 0);
  __builtin_amdgcn_s_setprio(0);
  if constexpr (MODE >= 1) {
#pragma unroll
    for (int m = 0; m < 4; ++m)
#pragma unroll
      for (int kk = 0; kk < 2; ++kk)
        aCur[m * 2 + kk] = RD(lAn, wr * 128 + m * 16 + l15, kk);
  }
  __builtin_amdgcn_s_barrier();
}

__global__ __launch_bounds__(512, 2) void gemm8(
    const unsigned short* __restrict__ A,   // [Ndim][Edim] bf16
    const unsigned short* __restrict__ Bt,  // [Bdim][Fdim][Edim] bf16
    float* __restrict__ C) {                // [Bdim][Ndim][Fdim] f32
  // LDS: buf0.A=0 (h1 +16384) buf0.B.h0=32768 buf0.B.h1=49152
  //      buf1.A=65536 (h1 +16384) buf1.B.h0=98304 buf1.B.h1=114688
  __shared__ __align__(16) char smem[131072];

  const int bid = blockIdx.x;
  const int lid = ((bid & 7) << 5) | (bid >> 3);  // XCD-contiguous (256 % 8 == 0)
  const int mt = lid >> 4;   // node tile 0..15
  const int bb = lid & 15;   // batch

  const int tid = threadIdx.x;
  const int lane = tid & 63;
  const int w = tid >> 6;
  const int wr = w >> 2;     // 0..1
  const int wc = w & 3;      // 0..3
  const int l15 = lane & 15;
  const int khi = (lane >> 4) << 4;

  const int r0 = tid >> 3;                         // staging row 0..63
  const int c0 = ((tid & 7) ^ (r0 & 7)) << 4;      // pre-swizzled 16B source column

  const char* Ag = (const char*)A + (size_t)(mt * 256) * EB + (size_t)r0 * EB + c0;
  const char* Bg = (const char*)Bt + (size_t)(bb * 256) * EB + (size_t)r0 * EB + c0;
  char* dst = smem + tid * 16;

  f32x4 acc[8][4];
#pragma unroll
  for (int m = 0; m < 8; ++m)
#pragma unroll
    for (int n = 0; n < 4; ++n) acc[m][n] = (f32x4){0.f, 0.f, 0.f, 0.f};

  const size_t HEB = (size_t)128 * EB;  // half-tile row offset in bytes

  // prologue: t0 full -> buf0, t1.B -> buf1.B (12 loads); wait t0 (vmcnt(4))
  stage_half(Ag, dst);
  stage_half(Ag + HEB, dst + 16384);
  stage_half(Bg, dst + 32768);
  stage_half(Bg + HEB, dst + 49152);
  stage_half(Bg + 128, dst + 98304);
  stage_half(Bg + 128 + HEB, dst + 114688);
  asm volatile("s_waitcnt vmcnt(4)" ::: "memory");
  __builtin_amdgcn_s_barrier();

  // pre-read t0's aLo + bLo (the carried P1 inputs)
  bf16x8 aCur[8];
  bf16x8 bLoC[4];
#pragma unroll
  for (int m = 0; m < 4; ++m)
#pragma unroll
    for (int kk = 0; kk < 2; ++kk)
      aCur[m * 2 + kk] = RD((const char*)smem, wr * 128 + m * 16 + l15, kk);
#pragma unroll
  for (int n = 0; n < 2; ++n)
#pragma unroll
    for (int kk = 0; kk < 2; ++kk)
      bLoC[n * 2 + kk] = RD((const char*)smem + 32768, wc * 64 + n * 16 + l15, kk);

  for (int i = 0; i < NT / 2 - 1; ++i) {
    const size_t t1b = (size_t)(2 * i + 1) * 128;
    const size_t t2b = (size_t)(2 * i + 2) * 128;
    const size_t t3b = (size_t)(2 * i + 3) * 128;
    // K-tile 2i on buf0; stages: (2i+1).A -> buf1.A, (2i+2).B -> buf0.B
    ktile<2>(smem, smem + 32768, smem + 65536, smem + 98304,
             dst + 65536, Ag + t1b,
             dst + 81920, Ag + t1b + HEB,
             dst + 32768, Bg + t2b,
             dst + 49152, Bg + t2b + HEB,
             lane, wr, wc, aCur, bLoC, acc);
    // K-tile 2i+1 on buf1; stages: (2i+2).A -> buf0.A, (2i+3).B -> buf1.B
    ktile<2>(smem + 65536, smem + 98304, smem, smem + 32768,
             dst, Ag + t2b,
             dst + 16384, Ag + t2b + HEB,
             dst + 98304, Bg + t3b,
             dst + 114688, Bg + t3b + HEB,
             lane, wr, wc, aCur, bLoC, acc);
  }
  // tail: tile NT-2 (buf0) stages (NT-1).A, vmcnt(0)@P3; tile NT-1 (buf1) bare
  {
    const size_t tlb = (size_t)(NT - 1) * 128;
    ktile<1>(smem, smem + 32768, smem + 65536, smem + 98304,
             dst + 65536, Ag + tlb,
             dst + 81920, Ag + tlb + HEB,
             nullptr, nullptr, nullptr, nullptr,
             lane, wr, wc, aCur, bLoC, acc);
    ktile<0>(smem + 65536, smem + 98304, nullptr, nullptr,
             nullptr, nullptr, nullptr, nullptr,
             nullptr, nullptr, nullptr, nullptr,
             lane, wr, wc, aCur, bLoC, acc);
  }

  float* Cb = C + (size_t)bb * (Ndim * Fdim) + (size_t)(mt * 256) * Fdim;
#pragma unroll
  for (int m = 0; m < 8; ++m) {
    int row0 = wr * 128 + m * 16 + ((lane >> 4) << 2);
#pragma unroll
    for (int n = 0; n < 4; ++n) {
      int col = wc * 64 + n * 16 + (lane & 15);
#pragma unroll
      for (int j = 0; j < 4; ++j)
        Cb[(size_t)(row0 + j) * Fdim + col] = acc[m][n][j];
    }
  }
}

// ---------------- fallback (ws too small): slow but correct fp32 ----------------
__global__ void naive_kernel(const float* __restrict__ x, const float* __restrict__ inci,
                             const float* __restrict__ w, const float* __restrict__ b,
                             float* __restrict__ out) {
  int n = blockIdx.x & (Ndim - 1);
  int bb = blockIdx.x >> 12;
  int f = threadIdx.x;
  const float* xb = x + (size_t)bb * Edim * Fdim;
  const size_t nE = (size_t)n * Edim;
  float acc = 0.f;
  for (int e = 0; e < Edim; e++) {
    float m = fmaf(w[nE + e], inci[nE + e], b[nE + e]);
    acc = fmaf(m, xb[(size_t)e * Fdim + f], acc);
  }
  out[(size_t)bb * Ndim * Fdim + (size_t)n * Fdim + f] = acc;
}

extern "C" void kernel_launch(void* const* d_in, const int* in_sizes, int n_in,
                              void* d_out, int out_size, void* d_ws, size_t ws_size,
                              hipStream_t stream) {
  const float* x = (const float*)d_in[0];
  const float* inci = (const float*)d_in[1];
  const float* w = (const float*)d_in[2];
  const float* b = (const float*)d_in[3];
  float* out = (float*)d_out;

  size_t mBytes = (size_t)Ndim * Edim * 2;
  size_t xTBytes = (size_t)Bdim * Fdim * Edim * 2;
  if (ws_size >= mBytes + xTBytes) {
    unsigned short* m_bf = (unsigned short*)d_ws;
    unsigned short* xT = m_bf + (size_t)Ndim * Edim;
    convert_m<<<(Ndim * (size_t)Edim) / 4 / 256, 256, 0, stream>>>(w, inci, b, m_bf);
    transpose_x<<<dim3(Edim / 64, Fdim / 64, Bdim), 256, 0, stream>>>(x, xT);
    gemm8<<<256, 512, 0, stream>>>(m_bf, xT, out);
  } else {
    naive_kernel<<<Bdim * Ndim, 256, 0, stream>>>(x, inci, w, b, out);
  }
}